// Round 6
// baseline (42.429 us; speedup 1.0000x reference)
//
#include <hip/hip_runtime.h>
#include <math.h>

typedef float f2 __attribute__((ext_vector_type(2)));

#define HH 32
#define WW 32
#define PAD 34          // padded scalar r plane
#define PADW 34         // padded width (f2 units) of final shifted v plane
#define VROWS 17
#define CHQ 10
#define SBS 10

// packed f32 fma, weight pair in %2, broadcast LOW half to both lanes
static __device__ __forceinline__ double pkfma_lo(double a, double w, double c) {
    double d;
    asm("v_pk_fma_f32 %0, %1, %2, %3 op_sel:[0,0,0] op_sel_hi:[1,0,1]"
        : "=v"(d) : "v"(a), "v"(w), "v"(c));
    return d;
}
static __device__ __forceinline__ double pkfma_hi(double a, double w, double c) {
    double d;
    asm("v_pk_fma_f32 %0, %1, %2, %3 op_sel:[0,1,0] op_sel_hi:[1,1,1]"
        : "=v"(d) : "v"(a), "v"(w), "v"(c));
    return d;
}
// no v_pk_max_f32 on gfx950 (CDNA packed-f32 is fma/add/mul only) -> 2x v_max_f32
static __device__ __forceinline__ double pkmax(double a, double b) {
    f2 af = __builtin_bit_cast(f2, a), bf = __builtin_bit_cast(f2, b);
    f2 r; r.x = fmaxf(af.x, bf.x); r.y = fmaxf(af.y, bf.y);
    return __builtin_bit_cast(double, r);
}
static __device__ __forceinline__ float bperm(int idx, float v) {
    return __builtin_bit_cast(float,
        __builtin_amdgcn_ds_bpermute(idx, __builtin_bit_cast(int, v)));
}
static __device__ __forceinline__ double d_of(float lo, float hi) {
    f2 t; t.x = lo; t.y = hi; return __builtin_bit_cast(double, t);
}

__global__ __launch_bounds__(512) void vin_kernel(
    const float* __restrict__ X,     // (bs,2,32,32)
    const int*   __restrict__ S1,    // (bs,10)
    const int*   __restrict__ S2,    // (bs,10)
    const float* __restrict__ bias,  // (150)
    const float* __restrict__ w0,    // (150,2,3,3)
    const float* __restrict__ w1,    // (150)
    const float* __restrict__ w,     // (10,1,3,3)
    const float* __restrict__ wfb,   // (10,1,3,3)
    const float* __restrict__ wo,    // (8,10)
    float* __restrict__ out,
    int bs)
{
    __shared__ float r_lds[PAD * PAD];
    __shared__ f2    vplane[VROWS * PADW];  // final v, shifted pairs (for gather)
    __shared__ float htop[2][10][32];       // [buf][wave+1][x] published top row (4w)
    __shared__ float hbot[2][10][32];       // [buf][wave+1][x] published bottom row (4w+3)
    __shared__ float weff[19];
    __shared__ float wpart[152];

    const int tid = threadIdx.x;
    const int b   = blockIdx.x;

    // ---- zero LDS (guards stay zero = SAME padding) ----
    for (int i = tid; i < PAD * PAD; i += 512) r_lds[i] = 0.f;
    {
        const f2 z = (f2)(0.f);
        for (int i = tid; i < VROWS * PADW; i += 512) vplane[i] = z;
        float* hz = &htop[0][0][0];
        for (int i = tid; i < 2 * 2 * 10 * 32; i += 512) hz[i] = 0.f;
    }

    // ---- collapse (w0,bias) x w1 into an effective 2ch 3x3 conv ----
    if (tid < 152) {
        const int o = tid >> 3;
        const int p = tid & 7;
        float s = 0.f;
        if (o < 18) {
            for (int c = p; c < 150; c += 8) s += w1[c] * w0[c * 18 + o];
        } else {
            for (int c = p; c < 150; c += 8) s += w1[c] * bias[c];
        }
        wpart[tid] = s;
    }
    __syncthreads();
    if (tid < 19) {
        float s = 0.f;
        #pragma unroll
        for (int p = 0; p < 8; ++p) s += wpart[tid * 8 + p];
        weff[tid] = s;
    }
    __syncthreads();

    // ---- thread geometry ----
    const int lane  = tid & 63;
    const int x     = tid & 31;
    const int wv    = tid >> 6;            // wave 0..7, owns rows 4wv..4wv+3
    const int upper = (lane >> 5) & 1;     // half-wave: 0 -> rows {4w,4w+1}, 1 -> {4w+2,4w+3}
    const int m     = tid >> 5;            // pair row 0..15, y0 = 2m
    const int y0    = 2 * m;
    const int cx    = x + 1;
    const int idxL  = ((lane - 1) & 63) << 2;
    const int idxR  = ((lane + 1) & 63) << 2;
    const int idxS  = (lane ^ 32) << 2;
    const bool xe0  = (x == 0);
    const bool xe31 = (x == 31);

    float we[19];
    #pragma unroll
    for (int i = 0; i < 19; ++i) we[i] = weff[i];

    // ---- r = conv(X, w_eff) + b_eff (2 rows per thread) ----
    const float* Xb = X + (size_t)b * 2 * HH * WW;
    #pragma unroll
    for (int dy = 0; dy < 2; ++dy) {
        const int y = y0 + dy;
        float acc = we[18];
        #pragma unroll
        for (int ci = 0; ci < 2; ++ci)
        #pragma unroll
        for (int ky = 0; ky < 3; ++ky)
        #pragma unroll
        for (int kx = 0; kx < 3; ++kx) {
            const int yy = y + ky - 1, xx = x + kx - 1;
            const float xv = (yy >= 0 && yy < HH && xx >= 0 && xx < WW)
                           ? Xb[ci * (HH * WW) + yy * WW + xx] : 0.f;
            acc += we[ci * 9 + ky * 3 + kx] * xv;
        }
        r_lds[(y + 1) * PAD + cx] = acc;
    }
    __syncthreads();

    // ---- qr = conv(r, w), v0 = max_oc qr ----
    float wr[CHQ][9];
    #pragma unroll
    for (int oc = 0; oc < CHQ; ++oc)
    #pragma unroll
    for (int k = 0; k < 9; ++k) wr[oc][k] = w[oc * 9 + k];

    float nb[4][3];
    #pragma unroll
    for (int rr = 0; rr < 4; ++rr)
    #pragma unroll
    for (int cc = 0; cc < 3; ++cc) nb[rr][cc] = r_lds[(y0 + rr) * PAD + (x + cc)];

    double qrd[CHQ];
    #pragma unroll
    for (int oc = 0; oc < CHQ; ++oc) {
        float t0 = 0.f, t1 = 0.f;
        #pragma unroll
        for (int ky = 0; ky < 3; ++ky)
        #pragma unroll
        for (int kx = 0; kx < 3; ++kx) {
            t0 += wr[oc][ky * 3 + kx] * nb[0 + ky][kx];
            t1 += wr[oc][ky * 3 + kx] * nb[1 + ky][kx];
        }
        qrd[oc] = d_of(t0, t1);
    }
    double P = qrd[0];
    #pragma unroll
    for (int oc = 1; oc < CHQ; ++oc) P = pkmax(P, qrd[oc]);
    // P = {v[2m], v[2m+1]} in registers from here on.

    // ---- packed w_fb pairs ----
    double WF[45];
    #pragma unroll
    for (int p = 0; p < 45; ++p) WF[p] = ((const double*)wfb)[p];

#define PK(kc, a, c) (((kc) & 1) ? pkfma_hi((a), WF[(kc) >> 1], (c)) \
                                 : pkfma_lo((a), WF[(kc) >> 1], (c)))

    // ---- one VI step: v <- max_oc(qr + conv(v, w_fb)), 1 barrier ----
#define STEP(BUF) do {                                                        \
        const f2 Pf = __builtin_bit_cast(f2, P);                              \
        /* publish own boundary row of current v */                           \
        { float* pa = upper ? &hbot[BUF][wv + 1][x] : &htop[BUF][wv + 1][x];  \
          *pa = upper ? Pf.y : Pf.x; }                                        \
        /* in-wave vertical partner: lower exports P.y, upper exports P.x */  \
        const float t_in  = bperm(idxS, upper ? Pf.x : Pf.y);                 \
        const float t_inL = xe0 ? 0.f : bperm(idxL, t_in);                    \
        const float t_inR = xe31 ? 0.f : bperm(idxR, t_in);                   \
        f2 PLf, PRf;                                                          \
        PLf.x = xe0 ? 0.f : bperm(idxL, Pf.x);                                \
        PLf.y = xe0 ? 0.f : bperm(idxL, Pf.y);                                \
        PRf.x = xe31 ? 0.f : bperm(idxR, Pf.x);                               \
        PRf.y = xe31 ? 0.f : bperm(idxR, Pf.y);                               \
        const double PLd = __builtin_bit_cast(double, PLf);                   \
        const double PRd = __builtin_bit_cast(double, PRf);                   \
        /* pre-barrier: ky=1 row of FMAs (register-only) */                   \
        double t[CHQ];                                                        \
        _Pragma("unroll")                                                     \
        for (int oc = 0; oc < CHQ; ++oc) {                                    \
            double tt = qrd[oc];                                              \
            tt = PK(oc * 9 + 3, PLd, tt);                                     \
            tt = PK(oc * 9 + 4, P,   tt);                                     \
            tt = PK(oc * 9 + 5, PRd, tt);                                     \
            t[oc] = tt;                                                       \
        }                                                                     \
        __syncthreads();                                                      \
        /* cross-wave halo: 1 float per thread */                             \
        const float lv  = upper ? htop[BUF][wv + 2][x] : hbot[BUF][wv][x];    \
        const float lvL = xe0 ? 0.f : bperm(idxL, lv);                        \
        const float lvR = xe31 ? 0.f : bperm(idxR, lv);                       \
        const float ttC = upper ? t_in  : lv;                                 \
        const float ttL = upper ? t_inL : lvL;                                \
        const float ttR = upper ? t_inR : lvR;                                \
        const float tbC = upper ? lv  : t_in;                                 \
        const float tbL = upper ? lvL : t_inL;                                \
        const float tbR = upper ? lvR : t_inR;                                \
        const double a0C = d_of(ttC, Pf.x),  a2C = d_of(Pf.y, tbC);           \
        const double a0L = d_of(ttL, PLf.x), a2L = d_of(PLf.y, tbL);          \
        const double a0R = d_of(ttR, PRf.x), a2R = d_of(PRf.y, tbR);          \
        _Pragma("unroll")                                                     \
        for (int oc = 0; oc < CHQ; ++oc) {                                    \
            double tt = t[oc];                                                \
            tt = PK(oc * 9 + 0, a0L, tt);                                     \
            tt = PK(oc * 9 + 1, a0C, tt);                                     \
            tt = PK(oc * 9 + 2, a0R, tt);                                     \
            tt = PK(oc * 9 + 6, a2L, tt);                                     \
            tt = PK(oc * 9 + 7, a2C, tt);                                     \
            tt = PK(oc * 9 + 8, a2R, tt);                                     \
            t[oc] = tt;                                                       \
        }                                                                     \
        double vm = t[0];                                                     \
        _Pragma("unroll")                                                     \
        for (int oc = 1; oc < CHQ; ++oc) vm = pkmax(vm, t[oc]);               \
        P = vm;                                                               \
    } while (0)

    // 39 steps, alternating halo buffers
    #pragma unroll 1
    for (int itp = 0; itp < 19; ++itp) {
        STEP(0);
        STEP(1);
    }
    STEP(0);

    // ---- write final v plane (shifted pairs) for the gather ----
    {
        const f2 Pf = __builtin_bit_cast(f2, P);
        vplane[m * PADW + cx].y = Pf.x;           // row m : {v[2m-1], v[2m]}.y
        vplane[(m + 1) * PADW + cx].x = Pf.y;     // row m+1: {v[2m+1], v[2m+2]}.x
    }
    __syncthreads();

    // ---- final q at the 10 gather points; 10->8 matmul + softmax ----
    if (tid < SBS) {
        const int row = b * SBS + tid;
        const int s1 = S1[row];
        const int s2 = S2[row];

        float fq[CHQ];
        #pragma unroll
        for (int oc = 0; oc < CHQ; ++oc) {
            float t = 0.f;
            #pragma unroll
            for (int ky = 0; ky < 3; ++ky)
            #pragma unroll
            for (int kx = 0; kx < 3; ++kx) {
                const int yy = s1 + ky - 1;            // -1..32
                const int xx = s2 + kx - 1;            // -1..32
                const int rp = (yy + 1) >> 1;          // shifted pair row
                const int comp = (yy & 1) ^ 1;         // even row -> .y
                const float vv = vplane[rp * PADW + (xx + 1)][comp];
                t += w[oc * 9 + ky * 3 + kx]   * r_lds[(yy + 1) * PAD + (xx + 1)]
                   + wfb[oc * 9 + ky * 3 + kx] * vv;
            }
            fq[oc] = t;
        }

        float o8[8];
        float mx = -1e30f;
        #pragma unroll
        for (int o = 0; o < 8; ++o) {
            float t = 0.f;
            #pragma unroll
            for (int oc = 0; oc < CHQ; ++oc) t += fq[oc] * wo[o * 10 + oc];
            o8[o] = t;
            mx = fmaxf(mx, t);
        }
        float e[8];
        float es = 0.f;
        #pragma unroll
        for (int o = 0; o < 8; ++o) { e[o] = expf(o8[o] - mx); es += e[o]; }
        const float inv = 1.f / es;

        #pragma unroll
        for (int o = 0; o < 8; ++o) {
            out[(size_t)row * 8 + o] = o8[o];
            out[(size_t)bs * SBS * 8 + (size_t)row * 8 + o] = e[o] * inv;
        }
    }
}

extern "C" void kernel_launch(void* const* d_in, const int* in_sizes, int n_in,
                              void* d_out, int out_size, void* d_ws, size_t ws_size,
                              hipStream_t stream) {
    const float* X    = (const float*)d_in[0];
    const int*   S1   = (const int*)d_in[1];
    const int*   S2   = (const int*)d_in[2];
    const float* bias = (const float*)d_in[3];
    const float* w0   = (const float*)d_in[4];
    const float* w1   = (const float*)d_in[5];
    const float* w    = (const float*)d_in[6];
    const float* wfb  = (const float*)d_in[7];
    const float* wo   = (const float*)d_in[8];
    float* out        = (float*)d_out;

    const int bs = in_sizes[0] / (2 * HH * WW);   // 256

    vin_kernel<<<bs, 512, 0, stream>>>(X, S1, S2, bias, w0, w1, w, wfb, wo, out, bs);
}